// Round 9
// baseline (445.377 us; speedup 1.0000x reference)
//
#include <hip/hip_runtime.h>
#include <hip/hip_bf16.h>
#include <stdint.h>

#define BROWS 32768
#define LATENT 1024
#define HID 512

typedef float f32x4 __attribute__((ext_vector_type(4)));
typedef __bf16 bf16x8 __attribute__((ext_vector_type(8)));
typedef unsigned short us8 __attribute__((ext_vector_type(8)));

__device__ __forceinline__ void gload16(const void* g, void* l) {
  __builtin_amdgcn_global_load_lds(
      (__attribute__((address_space(1))) void*)g,
      (__attribute__((address_space(3))) void*)l, 16, 0, 0);
}

// hi/lo bf16 split: x ~= hi + lo, residual ~2^-17 * |x|
__device__ __forceinline__ void split_bf16(float x, unsigned short& hi, unsigned short& lo) {
  __bf16 h = (__bf16)x;
  float r = x - (float)h;
  __bf16 l = (__bf16)r;
  hi = __builtin_bit_cast(unsigned short, h);
  lo = __builtin_bit_cast(unsigned short, l);
}

__device__ __forceinline__ f32x4 mfma16(bf16x8 a, bf16x8 b, f32x4 c) {
  return __builtin_amdgcn_mfma_f32_16x16x32_bf16(a, b, c, 0, 0, 0);
}

__device__ __forceinline__ bf16x8 ldfrag(const void* p) {
  return __builtin_bit_cast(bf16x8, *(const us8*)p);
}

// ---- prep: W1 (1024x512 f32) -> fused swizzled W1F: [n][kt][8 slots of 16B] ----------
// logical slot ls<4: hi bf16 of k = kt*32 + ls*8 .. +8 ; ls>=4: lo of (ls-4) chunk.
// stored at phys slot p = ls ^ (n&7)  (pre-swizzle so gload_lds can be linear).
__global__ __launch_bounds__(256) void k_prep_w1f(const float* __restrict__ W1,
                                                  unsigned short* __restrict__ w1f) {
  const int n = blockIdx.x;   // 0..511
  const int t = threadIdx.x;  // 0..255
  const int kt = t >> 3, ls = t & 7;
  const int p = ls ^ (n & 7);
  const int k0 = kt * 32 + (ls & 3) * 8;
  unsigned short v[8];
#pragma unroll
  for (int e = 0; e < 8; e++) {
    const float x = W1[(size_t)(k0 + e) * HID + n];
    unsigned short h, q;
    split_bf16(x, h, q);
    v[e] = (ls < 4) ? h : q;
  }
  unsigned short* dst = w1f + ((size_t)n * 32 + kt) * 64 + p * 8;
  *(ushort4*)(dst) = make_ushort4(v[0], v[1], v[2], v[3]);
  *(ushort4*)(dst + 4) = make_ushort4(v[4], v[5], v[6], v[7]);
}

// ---------------- prep: W2 (512x92 f32) -> W2T hi/lo bf16 [128][512], rows>=92 zero ----
__global__ __launch_bounds__(256) void k_prep_w2t(const float* __restrict__ W2,
                                                  unsigned short* __restrict__ hi,
                                                  unsigned short* __restrict__ lo) {
  const int idx = blockIdx.x * 256 + threadIdx.x;  // 65536 = 128*512
  const int n = idx >> 9, k = idx & 511;
  const float v = (n < 92) ? W2[(size_t)k * 92 + n] : 0.0f;
  unsigned short h, l;
  split_bf16(v, h, l);
  hi[idx] = h;
  lo[idx] = l;
}

// ---------------- GEMM1: h = silu(z @ W1 + b1) -----------------------------------------
// Tile 128(M)x128(N), BK=32, 4 waves (2m x 2n), wave-tile 64x64. A direct global->reg
// (in-reg hi/lo split). B via LDS dbuf (2x16KB). R4-proven ledger scaled to 4+4:
//   vmcnt(4) [B(t) landed] -> barrier -> GLOAD_B(t+1) -> vmcnt(4) [A(t) landed]
//   -> SPLIT_A -> LOAD_A(t+1) -> COMPUTE(t)
// Grid 1024 = 4 blocks/CU (16 waves): independent barrier domains decorrelate stalls.
__global__ __launch_bounds__(256, 4) void k_gemm1(
    const float* __restrict__ z, const unsigned short* __restrict__ w1f,
    const float* __restrict__ b1,
    unsigned short* __restrict__ hh, unsigned short* __restrict__ hl) {
  extern __shared__ __align__(16) char lb[];

  const int tid = threadIdx.x;
  const int bid = blockIdx.x;
  const int swz = (bid & 7) * 128 + (bid >> 3);  // bijective XCD swizzle (1024 blocks)
  const int mb = swz >> 2, nbk = swz & 3;
  const int m0 = mb * 128, n0g = nbk * 128;

  const int wv = tid >> 6, l = tid & 63;
  const int wr = wv >> 1, wc = wv & 1;  // wave grid 2m x 2n
  const int l15 = l & 15, lg = l >> 4;
  const int xr = l15 & 7;

  // B frag read byte bases within a buffer (rows = n-local, 128B/row, slot^=(row&7))
  const int bhB = (wc * 64 + l15) * 128 + ((lg ^ xr) << 4);
  const int blB = (wc * 64 + l15) * 128 + ((((4 | lg) ^ xr)) << 4);

  // A direct loads: lane covers z[m0 + wr*64 + mf*16 + l15][kt*32 + lg*8 .. +8]
  const float* zb = z + (size_t)(m0 + wr * 64 + l15) * LATENT + lg * 8;

  // B staging: per-lane global src (pre-swizzled layout; linear LDS dest).
  // wave wv covers n-rows wv*32 + j*8 + (l>>3), j=0..3; phys slot l&7.
  const unsigned short* bsrc =
      w1f + ((size_t)(n0g + wv * 32 + (l >> 3)) * 32) * 64 + (l & 7) * 8;

  f32x4 acc[4][4] = {};
  float4 arl[4], arh[4];
  bf16x8 ah[4], alo[4];

#define LOAD_A(kt1)                                                           \
  {                                                                           \
    _Pragma("unroll") for (int mf = 0; mf < 4; mf++) {                        \
      const float* p_ = zb + (size_t)(16 * mf) * LATENT + (kt1) * 32;         \
      arl[mf] = *(const float4*)(p_);                                         \
      arh[mf] = *(const float4*)(p_ + 4);                                     \
    }                                                                         \
  }

#define SPLIT_A                                                               \
  {                                                                           \
    _Pragma("unroll") for (int mf = 0; mf < 4; mf++) {                        \
      _Pragma("unroll") for (int e = 0; e < 4; e++) {                         \
        float f0 = arl[mf][e], f1 = arh[mf][e];                               \
        __bf16 h0 = (__bf16)f0, h1 = (__bf16)f1;                              \
        ah[mf][e] = h0;     alo[mf][e] = (__bf16)(f0 - (float)h0);            \
        ah[mf][4 + e] = h1; alo[mf][4 + e] = (__bf16)(f1 - (float)h1);        \
      }                                                                       \
    }                                                                         \
  }

#define GLOAD_B(bufo, kt1)                                                    \
  {                                                                           \
    _Pragma("unroll") for (int j_ = 0; j_ < 4; j_++)                          \
        gload16(bsrc + (size_t)j_ * 16384 + (kt1) * 64,                       \
                lb + (bufo) + (wv * 32 + j_ * 8) * 128);                      \
  }

#define COMPUTE(bufo)                                                         \
  {                                                                           \
    __builtin_amdgcn_s_setprio(1);                                            \
    _Pragma("unroll") for (int nf = 0; nf < 4; nf++) {                        \
      bf16x8 bh = ldfrag(lb + (bufo) + bhB + nf * 2048);                      \
      _Pragma("unroll") for (int mf = 0; mf < 4; mf++)                        \
          acc[mf][nf] = mfma16(ah[mf], bh, acc[mf][nf]);                      \
      _Pragma("unroll") for (int mf = 0; mf < 4; mf++)                        \
          acc[mf][nf] = mfma16(alo[mf], bh, acc[mf][nf]);                     \
    }                                                                         \
    _Pragma("unroll") for (int nf = 0; nf < 4; nf++) {                        \
      bf16x8 bl = ldfrag(lb + (bufo) + blB + nf * 2048);                      \
      _Pragma("unroll") for (int mf = 0; mf < 4; mf++)                        \
          acc[mf][nf] = mfma16(ah[mf], bl, acc[mf][nf]);                      \
    }                                                                         \
    __builtin_amdgcn_s_setprio(0);                                            \
  }

  // ---- prologue: issue B(0) then A(0) ----
  GLOAD_B(0, 0);
  LOAD_A(0);

#pragma unroll 2
  for (int t = 0; t < 32; ++t) {
    const int cb = (t & 1) << 14;   // 16384
    const int nx = cb ^ 16384;

    asm volatile("s_waitcnt vmcnt(4)" ::: "memory");  // B(t) landed in LDS
    __builtin_amdgcn_s_barrier();                     // all waves have B(t); nxt free

    if (t < 31) {
      GLOAD_B(nx, t + 1);                             // 4 gloads, newest in ledger
      asm volatile("s_waitcnt vmcnt(4)" ::: "memory");  // A(t) regs landed
    } else {
      asm volatile("s_waitcnt vmcnt(0)" ::: "memory");
    }
    SPLIT_A;                                          // consume A(t) regs
    if (t < 31) LOAD_A(t + 1);                        // reuse arl/arh (WAR ordered)

    COMPUTE(cb);
  }

  // ---- epilogue: bias + silu + hi/lo split store ----
  float b1v[4];
#pragma unroll
  for (int nf = 0; nf < 4; nf++) b1v[nf] = b1[n0g + wc * 64 + nf * 16 + l15];

#pragma unroll
  for (int mf = 0; mf < 4; mf++)
#pragma unroll
    for (int nf = 0; nf < 4; nf++)
#pragma unroll
      for (int r = 0; r < 4; r++) {
        const int gm = m0 + wr * 64 + mf * 16 + (lg << 2) + r;
        const int gn = n0g + wc * 64 + nf * 16 + l15;
        const float x = acc[mf][nf][r] + b1v[nf];
        const float hval = x / (1.0f + expf(-x));  // silu
        unsigned short hi_, lo_;
        split_bf16(hval, hi_, lo_);
        const size_t o = (size_t)gm * HID + gn;
        hh[o] = hi_;
        hl[o] = lo_;
      }
}

// ---------------- GEMM2 + normalize/softplus/FK epilogue ------------------------------
__global__ __launch_bounds__(256, 2) void k_gemm2(
    const unsigned short* __restrict__ hh, const unsigned short* __restrict__ hl,
    const unsigned short* __restrict__ w2h, const unsigned short* __restrict__ w2l,
    const float* __restrict__ b2, float* __restrict__ out) {
  __shared__ unsigned short Ah[2][2048], Al[2][2048];  // [64][32]
  __shared__ unsigned short Bh[2][4096], Bl[2][4096];  // [128][32]
  __shared__ float raw[64][97];                        // +1 pad: no stride-96 conflicts

  const int tid = threadIdx.x;
  const int m0 = blockIdx.x * 64;
  const int w = tid >> 6, lane = tid & 63;
  const int wr = w >> 1, wc = w & 1;
  const int l15 = lane & 15, lg = lane >> 4;
  const int arow = tid >> 2, ac8 = (tid & 3) << 3;

  const unsigned short* hhb = hh + (size_t)(m0 + arow) * HID + ac8;
  const unsigned short* hlb = hl + (size_t)(m0 + arow) * HID + ac8;
  const unsigned short* w2hb = w2h + (size_t)arow * HID + ac8;
  const unsigned short* w2lb = w2l + (size_t)arow * HID + ac8;

  f32x4 acc[2][3] = {};

#define G2_STAGE(kt, bf) { \
    gload16(hhb + (kt) * 32, &Ah[bf][(w << 9)]); \
    gload16(hlb + (kt) * 32, &Al[bf][(w << 9)]); \
    gload16(w2hb + (kt) * 32,            &Bh[bf][(w << 9)]); \
    gload16(w2hb + (kt) * 32 + 64 * HID, &Bh[bf][2048 + (w << 9)]); \
    gload16(w2lb + (kt) * 32,            &Bl[bf][(w << 9)]); \
    gload16(w2lb + (kt) * 32 + 64 * HID, &Bl[bf][2048 + (w << 9)]); }

#define G2_COMPUTE(bf) { \
    bf16x8 ah2[2], al2[2], bh2[3], bl2[3]; \
    _Pragma("unroll") \
    for (int mf = 0; mf < 2; mf++) { \
      const int o_ = ((wr * 32 + mf * 16 + l15) << 5) + (lg << 3); \
      ah2[mf] = ldfrag(&Ah[bf][o_]); \
      al2[mf] = ldfrag(&Al[bf][o_]); \
    } \
    _Pragma("unroll") \
    for (int nf = 0; nf < 3; nf++) { \
      const int o_ = ((wc * 48 + nf * 16 + l15) << 5) + (lg << 3); \
      bh2[nf] = ldfrag(&Bh[bf][o_]); \
      bl2[nf] = ldfrag(&Bl[bf][o_]); \
    } \
    _Pragma("unroll") \
    for (int mf = 0; mf < 2; mf++) { \
      _Pragma("unroll") \
      for (int nf = 0; nf < 3; nf++) { \
        acc[mf][nf] = mfma16(ah2[mf], bh2[nf], acc[mf][nf]); \
        acc[mf][nf] = mfma16(al2[mf], bh2[nf], acc[mf][nf]); \
        acc[mf][nf] = mfma16(ah2[mf], bl2[nf], acc[mf][nf]); \
      } } }

  G2_STAGE(0, 0);
  __syncthreads();
#pragma unroll 2
  for (int kt = 0; kt < 16; kt++) {
    const int cur = kt & 1, nx = cur ^ 1;
    if (kt < 15) G2_STAGE(kt + 1, nx);
    G2_COMPUTE(cur);
    __syncthreads();
  }

  // acc -> raw LDS (raw = h @ W2, no bias yet; cols 92..95 are zero via W2T pad)
#pragma unroll
  for (int mf = 0; mf < 2; mf++) {
#pragma unroll
    for (int nf = 0; nf < 3; nf++) {
#pragma unroll
      for (int r = 0; r < 4; r++) {
        const int ml = wr * 32 + mf * 16 + (lg << 2) + r;
        const int nl = wc * 48 + nf * 16 + l15;
        raw[ml][nl] = acc[mf][nf][r];
      }
    }
  }
  __syncthreads();

  const size_t OFFB = (size_t)BROWS * 72;   // offsets section
  const size_t LENB = (size_t)BROWS * 144;  // length section

  // phase 1: per (row, joint) -> direction*length, write offsets+length, off in-place
  for (int task = tid; task < 64 * 24; task += 256) {
    const int row = task / 24;
    const int j = task - row * 24;
    const int gm = m0 + row;
    float* orow = out + OFFB + (size_t)gm * 72;
    if (j == 0) {
      orow[0] = 0.0f; orow[1] = 0.0f; orow[2] = 0.0f;
    } else {
      const int c0 = (j - 1) * 4;
      const float vx = raw[row][c0 + 0] + b2[c0 + 0];
      const float vy = raw[row][c0 + 1] + b2[c0 + 1];
      const float vz = raw[row][c0 + 2] + b2[c0 + 2];
      const float wvv = raw[row][c0 + 3] + b2[c0 + 3];
      const float nrm = sqrtf(vx * vx + vy * vy + vz * vz);
      const float inv = 1.0f / fmaxf(nrm, 1e-12f);
      const float len = fmaxf(wvv, 0.0f) + log1pf(expf(-fabsf(wvv)));  // softplus
      const float sc = inv * len;
      const float ox = vx * sc, oy = vy * sc, oz = vz * sc;
      orow[j * 3 + 0] = ox; orow[j * 3 + 1] = oy; orow[j * 3 + 2] = oz;
      out[LENB + (size_t)gm * 23 + (j - 1)] = len;
      raw[row][c0 + 0] = ox; raw[row][c0 + 1] = oy; raw[row][c0 + 2] = oz;
    }
  }
  __syncthreads();

  // phase 2: forward kinematics, one thread per row, fully static unroll
  if (tid < 64) {
    constexpr int PAR[24] = {-1, 0, 0, 0, 1, 2, 3, 4, 5, 6, 7, 8,
                             9, 9, 9, 12, 13, 14, 16, 17, 18, 19, 20, 21};
    const int gm = m0 + tid;
    float e[72];
    e[0] = 0.0f; e[1] = 0.0f; e[2] = 0.0f;
#pragma unroll
    for (int j = 1; j < 24; j++) {
      const int p = PAR[j];
      const int c0 = (j - 1) * 4;
      e[3 * j + 0] = e[3 * p + 0] + raw[tid][c0 + 0];
      e[3 * j + 1] = e[3 * p + 1] + raw[tid][c0 + 1];
      e[3 * j + 2] = e[3 * p + 2] + raw[tid][c0 + 2];
    }
    float4* jo = (float4*)(out + (size_t)gm * 72);
#pragma unroll
    for (int q = 0; q < 18; q++)
      jo[q] = make_float4(e[4 * q + 0], e[4 * q + 1], e[4 * q + 2], e[4 * q + 3]);
  }
}

extern "C" void kernel_launch(void* const* d_in, const int* in_sizes, int n_in,
                              void* d_out, int out_size, void* d_ws, size_t ws_size,
                              hipStream_t stream) {
  const float* z = (const float*)d_in[0];
  const float* W1 = (const float*)d_in[1];
  const float* b1 = (const float*)d_in[2];
  const float* W2 = (const float*)d_in[3];
  const float* b2 = (const float*)d_in[4];
  float* out = (float*)d_out;

  char* ws = (char*)d_ws;
  unsigned short* w1f = (unsigned short*)(ws);                                  // 2 MB
  unsigned short* w2h = (unsigned short*)(ws + (2 << 20));                      // 128 KB
  unsigned short* w2l = (unsigned short*)(ws + (2 << 20) + 131072);             // 128 KB
  unsigned short* hh = (unsigned short*)(ws + ((size_t)4 << 20));               // 32 MB
  unsigned short* hl = (unsigned short*)(ws + ((size_t)4 << 20) + ((size_t)32 << 20));  // 32 MB

  hipFuncSetAttribute((const void*)k_gemm1,
                      hipFuncAttributeMaxDynamicSharedMemorySize, 32768);

  hipLaunchKernelGGL(k_prep_w1f, dim3(512), dim3(256), 0, stream, W1, w1f);
  hipLaunchKernelGGL(k_prep_w2t, dim3(256), dim3(256), 0, stream, W2, w2h, w2l);
  hipLaunchKernelGGL(k_gemm1, dim3(1024), dim3(256), 32768, stream, z, w1f, b1, hh, hl);
  hipLaunchKernelGGL(k_gemm2, dim3(512), dim3(256), 0, stream, hh, hl, w2h, w2l, b2, out);
}

// Round 10
// 204.265 us; speedup vs baseline: 2.1804x; 2.1804x over previous
//
#include <hip/hip_runtime.h>
#include <hip/hip_bf16.h>
#include <stdint.h>

#define BROWS 32768
#define LATENT 1024
#define HID 512

typedef float f32x4 __attribute__((ext_vector_type(4)));
typedef __bf16 bf16x8 __attribute__((ext_vector_type(8)));
typedef unsigned short us8 __attribute__((ext_vector_type(8)));

__device__ __forceinline__ void gload16(const void* g, void* l) {
  __builtin_amdgcn_global_load_lds(
      (__attribute__((address_space(1))) void*)g,
      (__attribute__((address_space(3))) void*)l, 16, 0, 0);
}

// hi/lo bf16 split: x ~= hi + lo, residual ~2^-17 * |x|
__device__ __forceinline__ void split_bf16(float x, unsigned short& hi, unsigned short& lo) {
  __bf16 h = (__bf16)x;
  float r = x - (float)h;
  __bf16 l = (__bf16)r;
  hi = __builtin_bit_cast(unsigned short, h);
  lo = __builtin_bit_cast(unsigned short, l);
}

__device__ __forceinline__ f32x4 mfma16(bf16x8 a, bf16x8 b, f32x4 c) {
  return __builtin_amdgcn_mfma_f32_16x16x32_bf16(a, b, c, 0, 0, 0);
}

__device__ __forceinline__ bf16x8 ldfrag(const void* p) {
  return __builtin_bit_cast(bf16x8, *(const us8*)p);
}

// ---- prep: W1 (1024x512 f32) -> fused swizzled W1F: [n][kt][8 slots of 16B] ----------
// logical slot ls<4: hi bf16 of k = kt*32 + ls*8 .. +8 ; ls>=4: lo of (ls-4) chunk.
// stored at phys slot p = ls ^ (n&7)  (pre-swizzle so gload_lds can be linear).
__global__ __launch_bounds__(256) void k_prep_w1f(const float* __restrict__ W1,
                                                  unsigned short* __restrict__ w1f) {
  const int n = blockIdx.x;   // 0..511
  const int t = threadIdx.x;  // 0..255
  const int kt = t >> 3, ls = t & 7;
  const int p = ls ^ (n & 7);
  const int k0 = kt * 32 + (ls & 3) * 8;
  unsigned short v[8];
#pragma unroll
  for (int e = 0; e < 8; e++) {
    const float x = W1[(size_t)(k0 + e) * HID + n];
    unsigned short h, q;
    split_bf16(x, h, q);
    v[e] = (ls < 4) ? h : q;
  }
  unsigned short* dst = w1f + ((size_t)n * 32 + kt) * 64 + p * 8;
  *(ushort4*)(dst) = make_ushort4(v[0], v[1], v[2], v[3]);
  *(ushort4*)(dst + 4) = make_ushort4(v[4], v[5], v[6], v[7]);
}

// ---------------- prep: W2 (512x92 f32) -> W2T hi/lo bf16 [128][512], rows>=92 zero ----
__global__ __launch_bounds__(256) void k_prep_w2t(const float* __restrict__ W2,
                                                  unsigned short* __restrict__ hi,
                                                  unsigned short* __restrict__ lo) {
  const int idx = blockIdx.x * 256 + threadIdx.x;  // 65536 = 128*512
  const int n = idx >> 9, k = idx & 511;
  const float v = (n < 92) ? W2[(size_t)k * 92 + n] : 0.0f;
  unsigned short h, l;
  split_bf16(v, h, l);
  hi[idx] = h;
  lo[idx] = l;
}

// ---------------- GEMM1: h = silu(z @ W1 + b1) -----------------------------------------
// Tile 64(M)x256(N), BK=32, 4 waves (1m x 4n), wave-tile 64x64. All 4 waves read the
// SAME 8KB A-tile per iter (L1-hot); z re-read only 2x; B panels (2MB) L2-resident.
// A direct global->reg + in-reg hi/lo split; B via LDS dbuf (2x32KB). R4-proven ledger:
//   vmcnt(8) [B(t) landed] -> barrier -> GLOAD_B(t+1) -> vmcnt(8) [A(t) landed]
//   -> SPLIT_A -> LOAD_A(t+1) -> COMPUTE(t)
// 2 blocks/CU (two independent barrier domains), grid 1024 (2 rounds).
__global__ __launch_bounds__(256, 2) void k_gemm1(
    const float* __restrict__ z, const unsigned short* __restrict__ w1f,
    const float* __restrict__ b1,
    unsigned short* __restrict__ hh, unsigned short* __restrict__ hl) {
  extern __shared__ __align__(16) char lb[];

  const int tid = threadIdx.x;
  const int bid = blockIdx.x;
  const int swz = (bid & 7) * 128 + (bid >> 3);  // bijective XCD swizzle (1024 blocks)
  const int mb = swz >> 1, nbk = swz & 1;        // n-pair adjacent on same XCD
  const int m0 = mb * 64, n0g = nbk * 256;

  const int wv = tid >> 6, l = tid & 63;         // wave grid 1m x 4n: wc = wv
  const int l15 = l & 15, lg = l >> 4;
  const int xr = l15 & 7;

  // B frag read byte bases within a buffer (rows = n-local, 128B/row, slot^=(row&7))
  const int bhB = (wv * 64 + l15) * 128 + ((lg ^ xr) << 4);
  const int blB = (wv * 64 + l15) * 128 + ((((4 | lg) ^ xr)) << 4);

  // A direct loads: lane covers z[m0 + mf*16 + l15][kt*32 + lg*8 .. +8]  (all waves same)
  const float* zb = z + (size_t)(m0 + l15) * LATENT + lg * 8;

  // B staging: per-lane global src (pre-swizzled layout; linear LDS dest).
  // wave wv covers n-rows wv*64 + j*8 + (l>>3), j=0..7; phys slot l&7.
  const unsigned short* bsrc =
      w1f + ((size_t)(n0g + wv * 64 + (l >> 3)) * 32) * 64 + (l & 7) * 8;

  f32x4 acc[4][4] = {};
  float4 arl[4], arh[4];
  bf16x8 ah[4], alo[4];

#define LOAD_A(kt1)                                                           \
  {                                                                           \
    _Pragma("unroll") for (int mf = 0; mf < 4; mf++) {                        \
      const float* p_ = zb + (size_t)(16 * mf) * LATENT + (kt1) * 32;         \
      arl[mf] = *(const float4*)(p_);                                         \
      arh[mf] = *(const float4*)(p_ + 4);                                     \
    }                                                                         \
  }

#define SPLIT_A                                                               \
  {                                                                           \
    _Pragma("unroll") for (int mf = 0; mf < 4; mf++) {                        \
      _Pragma("unroll") for (int e = 0; e < 4; e++) {                         \
        float f0 = arl[mf][e], f1 = arh[mf][e];                               \
        __bf16 h0 = (__bf16)f0, h1 = (__bf16)f1;                              \
        ah[mf][e] = h0;     alo[mf][e] = (__bf16)(f0 - (float)h0);            \
        ah[mf][4 + e] = h1; alo[mf][4 + e] = (__bf16)(f1 - (float)h1);        \
      }                                                                       \
    }                                                                         \
  }

#define GLOAD_B(bufo, kt1)                                                    \
  {                                                                           \
    _Pragma("unroll") for (int j_ = 0; j_ < 8; j_++)                          \
        gload16(bsrc + (size_t)j_ * 16384 + (kt1) * 64,                       \
                lb + (bufo) + (wv * 64 + j_ * 8) * 128);                      \
  }

#define COMPUTE(bufo)                                                         \
  {                                                                           \
    __builtin_amdgcn_s_setprio(1);                                            \
    _Pragma("unroll") for (int nf = 0; nf < 4; nf++) {                        \
      bf16x8 bh = ldfrag(lb + (bufo) + bhB + nf * 2048);                      \
      _Pragma("unroll") for (int mf = 0; mf < 4; mf++)                        \
          acc[mf][nf] = mfma16(ah[mf], bh, acc[mf][nf]);                      \
      _Pragma("unroll") for (int mf = 0; mf < 4; mf++)                        \
          acc[mf][nf] = mfma16(alo[mf], bh, acc[mf][nf]);                     \
    }                                                                         \
    _Pragma("unroll") for (int nf = 0; nf < 4; nf++) {                        \
      bf16x8 bl = ldfrag(lb + (bufo) + blB + nf * 2048);                      \
      _Pragma("unroll") for (int mf = 0; mf < 4; mf++)                        \
          acc[mf][nf] = mfma16(ah[mf], bl, acc[mf][nf]);                      \
    }                                                                         \
    __builtin_amdgcn_s_setprio(0);                                            \
  }

  // ---- prologue: issue B(0) then A(0): ledger [B0 8, A0 8] ----
  GLOAD_B(0, 0);
  LOAD_A(0);

#pragma unroll 2
  for (int t = 0; t < 32; ++t) {
    const int cb = (t & 1) << 15;   // 32768
    const int nx = cb ^ 32768;

    asm volatile("s_waitcnt vmcnt(8)" ::: "memory");  // B(t) landed in LDS
    __builtin_amdgcn_s_barrier();                     // all waves have B(t); nxt free

    if (t < 31) {
      GLOAD_B(nx, t + 1);                             // 8 gloads, newest in ledger
      asm volatile("s_waitcnt vmcnt(8)" ::: "memory");  // A(t) regs landed
    } else {
      asm volatile("s_waitcnt vmcnt(0)" ::: "memory");
    }
    SPLIT_A;                                          // consume A(t) regs
    if (t < 31) LOAD_A(t + 1);                        // reuse arl/arh (WAR ordered)

    COMPUTE(cb);
  }

  // ---- epilogue: bias + silu + hi/lo split store ----
  float b1v[4];
#pragma unroll
  for (int nf = 0; nf < 4; nf++) b1v[nf] = b1[n0g + wv * 64 + nf * 16 + l15];

#pragma unroll
  for (int mf = 0; mf < 4; mf++)
#pragma unroll
    for (int nf = 0; nf < 4; nf++)
#pragma unroll
      for (int r = 0; r < 4; r++) {
        const int gm = m0 + mf * 16 + (lg << 2) + r;
        const int gn = n0g + wv * 64 + nf * 16 + l15;
        const float x = acc[mf][nf][r] + b1v[nf];
        const float hval = x / (1.0f + expf(-x));  // silu
        unsigned short hi_, lo_;
        split_bf16(hval, hi_, lo_);
        const size_t o = (size_t)gm * HID + gn;
        hh[o] = hi_;
        hl[o] = lo_;
      }
}

// ---------------- GEMM2 + normalize/softplus/FK epilogue ------------------------------
__global__ __launch_bounds__(256, 2) void k_gemm2(
    const unsigned short* __restrict__ hh, const unsigned short* __restrict__ hl,
    const unsigned short* __restrict__ w2h, const unsigned short* __restrict__ w2l,
    const float* __restrict__ b2, float* __restrict__ out) {
  __shared__ unsigned short Ah[2][2048], Al[2][2048];  // [64][32]
  __shared__ unsigned short Bh[2][4096], Bl[2][4096];  // [128][32]
  __shared__ float raw[64][97];                        // +1 pad: no stride-96 conflicts

  const int tid = threadIdx.x;
  const int m0 = blockIdx.x * 64;
  const int w = tid >> 6, lane = tid & 63;
  const int wr = w >> 1, wc = w & 1;
  const int l15 = lane & 15, lg = lane >> 4;
  const int arow = tid >> 2, ac8 = (tid & 3) << 3;

  const unsigned short* hhb = hh + (size_t)(m0 + arow) * HID + ac8;
  const unsigned short* hlb = hl + (size_t)(m0 + arow) * HID + ac8;
  const unsigned short* w2hb = w2h + (size_t)arow * HID + ac8;
  const unsigned short* w2lb = w2l + (size_t)arow * HID + ac8;

  f32x4 acc[2][3] = {};

#define G2_STAGE(kt, bf) { \
    gload16(hhb + (kt) * 32, &Ah[bf][(w << 9)]); \
    gload16(hlb + (kt) * 32, &Al[bf][(w << 9)]); \
    gload16(w2hb + (kt) * 32,            &Bh[bf][(w << 9)]); \
    gload16(w2hb + (kt) * 32 + 64 * HID, &Bh[bf][2048 + (w << 9)]); \
    gload16(w2lb + (kt) * 32,            &Bl[bf][(w << 9)]); \
    gload16(w2lb + (kt) * 32 + 64 * HID, &Bl[bf][2048 + (w << 9)]); }

#define G2_COMPUTE(bf) { \
    bf16x8 ah2[2], al2[2], bh2[3], bl2[3]; \
    _Pragma("unroll") \
    for (int mf = 0; mf < 2; mf++) { \
      const int o_ = ((wr * 32 + mf * 16 + l15) << 5) + (lg << 3); \
      ah2[mf] = ldfrag(&Ah[bf][o_]); \
      al2[mf] = ldfrag(&Al[bf][o_]); \
    } \
    _Pragma("unroll") \
    for (int nf = 0; nf < 3; nf++) { \
      const int o_ = ((wc * 48 + nf * 16 + l15) << 5) + (lg << 3); \
      bh2[nf] = ldfrag(&Bh[bf][o_]); \
      bl2[nf] = ldfrag(&Bl[bf][o_]); \
    } \
    _Pragma("unroll") \
    for (int mf = 0; mf < 2; mf++) { \
      _Pragma("unroll") \
      for (int nf = 0; nf < 3; nf++) { \
        acc[mf][nf] = mfma16(ah2[mf], bh2[nf], acc[mf][nf]); \
        acc[mf][nf] = mfma16(al2[mf], bh2[nf], acc[mf][nf]); \
        acc[mf][nf] = mfma16(ah2[mf], bl2[nf], acc[mf][nf]); \
      } } }

  G2_STAGE(0, 0);
  __syncthreads();
#pragma unroll 2
  for (int kt = 0; kt < 16; kt++) {
    const int cur = kt & 1, nx = cur ^ 1;
    if (kt < 15) G2_STAGE(kt + 1, nx);
    G2_COMPUTE(cur);
    __syncthreads();
  }

  // acc -> raw LDS (raw = h @ W2, no bias yet; cols 92..95 are zero via W2T pad)
#pragma unroll
  for (int mf = 0; mf < 2; mf++) {
#pragma unroll
    for (int nf = 0; nf < 3; nf++) {
#pragma unroll
      for (int r = 0; r < 4; r++) {
        const int ml = wr * 32 + mf * 16 + (lg << 2) + r;
        const int nl = wc * 48 + nf * 16 + l15;
        raw[ml][nl] = acc[mf][nf][r];
      }
    }
  }
  __syncthreads();

  const size_t OFFB = (size_t)BROWS * 72;   // offsets section
  const size_t LENB = (size_t)BROWS * 144;  // length section

  // phase 1: per (row, joint) -> direction*length, write offsets+length, off in-place
  for (int task = tid; task < 64 * 24; task += 256) {
    const int row = task / 24;
    const int j = task - row * 24;
    const int gm = m0 + row;
    float* orow = out + OFFB + (size_t)gm * 72;
    if (j == 0) {
      orow[0] = 0.0f; orow[1] = 0.0f; orow[2] = 0.0f;
    } else {
      const int c0 = (j - 1) * 4;
      const float vx = raw[row][c0 + 0] + b2[c0 + 0];
      const float vy = raw[row][c0 + 1] + b2[c0 + 1];
      const float vz = raw[row][c0 + 2] + b2[c0 + 2];
      const float wvv = raw[row][c0 + 3] + b2[c0 + 3];
      const float nrm = sqrtf(vx * vx + vy * vy + vz * vz);
      const float inv = 1.0f / fmaxf(nrm, 1e-12f);
      const float len = fmaxf(wvv, 0.0f) + log1pf(expf(-fabsf(wvv)));  // softplus
      const float sc = inv * len;
      const float ox = vx * sc, oy = vy * sc, oz = vz * sc;
      orow[j * 3 + 0] = ox; orow[j * 3 + 1] = oy; orow[j * 3 + 2] = oz;
      out[LENB + (size_t)gm * 23 + (j - 1)] = len;
      raw[row][c0 + 0] = ox; raw[row][c0 + 1] = oy; raw[row][c0 + 2] = oz;
    }
  }
  __syncthreads();

  // phase 2: forward kinematics, one thread per row, fully static unroll
  if (tid < 64) {
    constexpr int PAR[24] = {-1, 0, 0, 0, 1, 2, 3, 4, 5, 6, 7, 8,
                             9, 9, 9, 12, 13, 14, 16, 17, 18, 19, 20, 21};
    const int gm = m0 + tid;
    float e[72];
    e[0] = 0.0f; e[1] = 0.0f; e[2] = 0.0f;
#pragma unroll
    for (int j = 1; j < 24; j++) {
      const int p = PAR[j];
      const int c0 = (j - 1) * 4;
      e[3 * j + 0] = e[3 * p + 0] + raw[tid][c0 + 0];
      e[3 * j + 1] = e[3 * p + 1] + raw[tid][c0 + 1];
      e[3 * j + 2] = e[3 * p + 2] + raw[tid][c0 + 2];
    }
    float4* jo = (float4*)(out + (size_t)gm * 72);
#pragma unroll
    for (int q = 0; q < 18; q++)
      jo[q] = make_float4(e[4 * q + 0], e[4 * q + 1], e[4 * q + 2], e[4 * q + 3]);
  }
}

extern "C" void kernel_launch(void* const* d_in, const int* in_sizes, int n_in,
                              void* d_out, int out_size, void* d_ws, size_t ws_size,
                              hipStream_t stream) {
  const float* z = (const float*)d_in[0];
  const float* W1 = (const float*)d_in[1];
  const float* b1 = (const float*)d_in[2];
  const float* W2 = (const float*)d_in[3];
  const float* b2 = (const float*)d_in[4];
  float* out = (float*)d_out;

  char* ws = (char*)d_ws;
  unsigned short* w1f = (unsigned short*)(ws);                                  // 2 MB
  unsigned short* w2h = (unsigned short*)(ws + (2 << 20));                      // 128 KB
  unsigned short* w2l = (unsigned short*)(ws + (2 << 20) + 131072);             // 128 KB
  unsigned short* hh = (unsigned short*)(ws + ((size_t)4 << 20));               // 32 MB
  unsigned short* hl = (unsigned short*)(ws + ((size_t)4 << 20) + ((size_t)32 << 20));  // 32 MB

  hipFuncSetAttribute((const void*)k_gemm1,
                      hipFuncAttributeMaxDynamicSharedMemorySize, 65536);

  hipLaunchKernelGGL(k_prep_w1f, dim3(512), dim3(256), 0, stream, W1, w1f);
  hipLaunchKernelGGL(k_prep_w2t, dim3(256), dim3(256), 0, stream, W2, w2h, w2l);
  hipLaunchKernelGGL(k_gemm1, dim3(1024), dim3(256), 65536, stream, z, w1f, b1, hh, hl);
  hipLaunchKernelGGL(k_gemm2, dim3(512), dim3(256), 0, stream, hh, hl, w2h, w2l, b2, out);
}

// Round 11
// 153.441 us; speedup vs baseline: 2.9026x; 1.3312x over previous
//
#include <hip/hip_runtime.h>
#include <hip/hip_bf16.h>
#include <stdint.h>

#define BROWS 32768
#define LATENT 1024
#define HID 512

typedef float f32x4 __attribute__((ext_vector_type(4)));
typedef float f32x16 __attribute__((ext_vector_type(16)));
typedef __bf16 bf16x8 __attribute__((ext_vector_type(8)));
typedef unsigned short us8 __attribute__((ext_vector_type(8)));

__device__ __forceinline__ void gload16(const void* g, void* l) {
  __builtin_amdgcn_global_load_lds(
      (__attribute__((address_space(1))) void*)g,
      (__attribute__((address_space(3))) void*)l, 16, 0, 0);
}

// hi/lo bf16 split: x ~= hi + lo, residual ~2^-17 * |x|
__device__ __forceinline__ void split_bf16(float x, unsigned short& hi, unsigned short& lo) {
  __bf16 h = (__bf16)x;
  float r = x - (float)h;
  __bf16 l = (__bf16)r;
  hi = __builtin_bit_cast(unsigned short, h);
  lo = __builtin_bit_cast(unsigned short, l);
}

__device__ __forceinline__ f32x4 mfma16(bf16x8 a, bf16x8 b, f32x4 c) {
  return __builtin_amdgcn_mfma_f32_16x16x32_bf16(a, b, c, 0, 0, 0);
}

__device__ __forceinline__ f32x16 mfma32(bf16x8 a, bf16x8 b, f32x16 c) {
  return __builtin_amdgcn_mfma_f32_32x32x16_bf16(a, b, c, 0, 0, 0);
}

__device__ __forceinline__ bf16x8 ldfrag(const void* p) {
  return __builtin_bit_cast(bf16x8, *(const us8*)p);
}

// ---- prep: W1 (1024x512 f32) -> fused swizzled W1F: [n][kt][8 slots of 16B] ----------
// logical slot ls<4: hi bf16 of k = kt*32 + ls*8 .. +8 ; ls>=4: lo of (ls-4) chunk.
// stored at phys slot p = ls ^ (n&7)  (pre-swizzle so gload_lds can be linear).
__global__ __launch_bounds__(256) void k_prep_w1f(const float* __restrict__ W1,
                                                  unsigned short* __restrict__ w1f) {
  const int n = blockIdx.x;   // 0..511
  const int t = threadIdx.x;  // 0..255
  const int kt = t >> 3, ls = t & 7;
  const int p = ls ^ (n & 7);
  const int k0 = kt * 32 + (ls & 3) * 8;
  unsigned short v[8];
#pragma unroll
  for (int e = 0; e < 8; e++) {
    const float x = W1[(size_t)(k0 + e) * HID + n];
    unsigned short h, q;
    split_bf16(x, h, q);
    v[e] = (ls < 4) ? h : q;
  }
  unsigned short* dst = w1f + ((size_t)n * 32 + kt) * 64 + p * 8;
  *(ushort4*)(dst) = make_ushort4(v[0], v[1], v[2], v[3]);
  *(ushort4*)(dst + 4) = make_ushort4(v[4], v[5], v[6], v[7]);
}

// ---------------- prep: W2 (512x92 f32) -> W2T hi/lo bf16 [128][512], rows>=92 zero ----
__global__ __launch_bounds__(256) void k_prep_w2t(const float* __restrict__ W2,
                                                  unsigned short* __restrict__ hi,
                                                  unsigned short* __restrict__ lo) {
  const int idx = blockIdx.x * 256 + threadIdx.x;  // 65536 = 128*512
  const int n = idx >> 9, k = idx & 511;
  const float v = (n < 92) ? W2[(size_t)k * 92 + n] : 0.0f;
  unsigned short h, l;
  split_bf16(v, h, l);
  hi[idx] = h;
  lo[idx] = l;
}

// ---------------- GEMM1: h = silu(z @ W1 + b1) -----------------------------------------
// R4 structure, 32x32x16 MFMA. Tile 128(M)x256(N), BK=32, 4 waves (2m x 2n),
// wave-tile 64x128 = 2(mt) x 4(nt) tiles of 32x32; 48 MFMA/K-tile/wave (3 terms).
// A direct global->reg + in-reg hi/lo split; B via LDS dbuf (2x32KB), R4-proven ledger:
//   vmcnt(8) [B(t) in LDS] -> barrier -> GLOAD_B(t+1) -> vmcnt(8) [A(t) regs]
//   -> SPLIT_A -> LOAD_A(t+1) -> COMPUTE(t)
// A frag (32x32x16): lane l covers row (l&31), k = (l>>5)*8 + e (+16 per k-frag).
// B frag: col (l&31), same k map -> logical slot (2f | l>>5), phys ^= (row&7).
// C/D: col=lane&31 (N), row=(reg&3)+8*(reg>>2)+4*(lane>>5) (M)  [m74/m101-verified].
__global__ __launch_bounds__(256, 2) void k_gemm1(
    const float* __restrict__ z, const unsigned short* __restrict__ w1f,
    const float* __restrict__ b1,
    unsigned short* __restrict__ hh, unsigned short* __restrict__ hl) {
  extern __shared__ __align__(16) char lb[];

  const int tid = threadIdx.x;
  const int bid = blockIdx.x;
  const int swz = (bid & 7) * 64 + (bid >> 3);  // bijective XCD swizzle (512 blocks)
  const int mb = swz >> 1, nbk = swz & 1;       // (mb, nbk) adjacent on same XCD
  const int m0 = mb * 128, n0g = nbk * 256;

  const int wv = tid >> 6, l = tid & 63;
  const int wr = wv >> 1, wc = wv & 1;  // wave grid 2m x 2n
  const int l31 = l & 31, lg5 = l >> 5, l7 = l & 7;

  // A direct loads: lane covers z[m0 + wr*64 + mt*32 + l31][kt*32 + f*16 + lg5*8 .. +8]
  const float* zb = z + (size_t)(m0 + wr * 64 + l31) * LATENT + lg5 * 8;

  // B staging: per-lane global src (pre-swizzled layout; linear LDS dest).
  // wave wv covers n-rows wv*64 + j*8 + (l>>3), j=0..7; phys slot l&7.
  const unsigned short* bsrc =
      w1f + ((size_t)(n0g + wv * 64 + (l >> 3)) * 32) * 64 + (l & 7) * 8;

  f32x16 acc[2][4] = {};
  float4 arl[2][2], arh[2][2];
  bf16x8 ah[2][2], alo[2][2];

#define LOAD_A(kt1)                                                           \
  {                                                                           \
    _Pragma("unroll") for (int mt = 0; mt < 2; mt++) {                        \
      _Pragma("unroll") for (int f = 0; f < 2; f++) {                         \
        const float* p_ = zb + (size_t)(32 * mt) * LATENT + (kt1) * 32 + f * 16; \
        arl[mt][f] = *(const float4*)(p_);                                    \
        arh[mt][f] = *(const float4*)(p_ + 4);                                \
      }                                                                       \
    }                                                                         \
  }

#define SPLIT_A                                                               \
  {                                                                           \
    _Pragma("unroll") for (int mt = 0; mt < 2; mt++) {                        \
      _Pragma("unroll") for (int f = 0; f < 2; f++) {                         \
        _Pragma("unroll") for (int e = 0; e < 4; e++) {                       \
          float f0 = arl[mt][f][e], f1 = arh[mt][f][e];                       \
          __bf16 h0 = (__bf16)f0, h1 = (__bf16)f1;                            \
          ah[mt][f][e] = h0;     alo[mt][f][e] = (__bf16)(f0 - (float)h0);    \
          ah[mt][f][4 + e] = h1; alo[mt][f][4 + e] = (__bf16)(f1 - (float)h1);\
        }                                                                     \
      }                                                                       \
    }                                                                         \
  }

#define GLOAD_B(bufo, kt1)                                                    \
  {                                                                           \
    _Pragma("unroll") for (int j_ = 0; j_ < 8; j_++)                          \
        gload16(bsrc + (size_t)j_ * 16384 + (kt1) * 64,                       \
                lb + (bufo) + (wv * 64 + j_ * 8) * 128);                      \
  }

#define COMPUTE(bufo)                                                         \
  {                                                                           \
    __builtin_amdgcn_s_setprio(1);                                            \
    _Pragma("unroll") for (int nt = 0; nt < 4; nt++) {                        \
      const char* rbase = lb + (bufo) + (wc * 128 + nt * 32 + l31) * 128;     \
      bf16x8 bh0 = ldfrag(rbase + ((lg5 ^ l7) << 4));                         \
      bf16x8 bh1 = ldfrag(rbase + (((2 | lg5) ^ l7) << 4));                   \
      acc[0][nt] = mfma32(ah[0][0], bh0, acc[0][nt]);                         \
      acc[1][nt] = mfma32(ah[1][0], bh0, acc[1][nt]);                         \
      acc[0][nt] = mfma32(ah[0][1], bh1, acc[0][nt]);                         \
      acc[1][nt] = mfma32(ah[1][1], bh1, acc[1][nt]);                         \
      acc[0][nt] = mfma32(alo[0][0], bh0, acc[0][nt]);                        \
      acc[1][nt] = mfma32(alo[1][0], bh0, acc[1][nt]);                        \
      acc[0][nt] = mfma32(alo[0][1], bh1, acc[0][nt]);                        \
      acc[1][nt] = mfma32(alo[1][1], bh1, acc[1][nt]);                        \
      bf16x8 bl0 = ldfrag(rbase + (((4 | lg5) ^ l7) << 4));                   \
      bf16x8 bl1 = ldfrag(rbase + (((6 | lg5) ^ l7) << 4));                   \
      acc[0][nt] = mfma32(ah[0][0], bl0, acc[0][nt]);                         \
      acc[1][nt] = mfma32(ah[1][0], bl0, acc[1][nt]);                         \
      acc[0][nt] = mfma32(ah[0][1], bl1, acc[0][nt]);                         \
      acc[1][nt] = mfma32(ah[1][1], bl1, acc[1][nt]);                         \
    }                                                                         \
    __builtin_amdgcn_s_setprio(0);                                            \
  }

  // ---- prologue: issue B(0) then A(0): ledger [B0 8, A0 8] ----
  GLOAD_B(0, 0);
  LOAD_A(0);

#pragma unroll 2
  for (int t = 0; t < 32; ++t) {
    const int cb = (t & 1) << 15;   // 32768
    const int nx = cb ^ 32768;

    asm volatile("s_waitcnt vmcnt(8)" ::: "memory");  // B(t) landed in LDS
    __builtin_amdgcn_s_barrier();                     // all waves have B(t); nxt free

    if (t < 31) {
      GLOAD_B(nx, t + 1);                             // 8 gloads, newest in ledger
      asm volatile("s_waitcnt vmcnt(8)" ::: "memory");  // A(t) regs landed
    } else {
      asm volatile("s_waitcnt vmcnt(0)" ::: "memory");
    }
    SPLIT_A;                                          // consume A(t) regs
    if (t < 31) LOAD_A(t + 1);                        // reuse arl/arh (WAR ordered)

    COMPUTE(cb);
  }

  // ---- epilogue: bias + silu + hi/lo split store ----
  float b1v[4];
#pragma unroll
  for (int nt = 0; nt < 4; nt++) b1v[nt] = b1[n0g + wc * 128 + nt * 32 + l31];

#pragma unroll
  for (int mt = 0; mt < 2; mt++)
#pragma unroll
    for (int nt = 0; nt < 4; nt++)
#pragma unroll
      for (int r = 0; r < 16; r++) {
        const int row = (r & 3) + 8 * (r >> 2) + 4 * lg5;
        const int gm = m0 + wr * 64 + mt * 32 + row;
        const int gn = n0g + wc * 128 + nt * 32 + l31;
        const float x = acc[mt][nt][r] + b1v[nt];
        const float hval = x / (1.0f + expf(-x));  // silu
        unsigned short hi_, lo_;
        split_bf16(hval, hi_, lo_);
        const size_t o = (size_t)gm * HID + gn;
        hh[o] = hi_;
        hl[o] = lo_;
      }
}

// ---------------- GEMM2 + normalize/softplus/FK epilogue ------------------------------
__global__ __launch_bounds__(256, 2) void k_gemm2(
    const unsigned short* __restrict__ hh, const unsigned short* __restrict__ hl,
    const unsigned short* __restrict__ w2h, const unsigned short* __restrict__ w2l,
    const float* __restrict__ b2, float* __restrict__ out) {
  __shared__ unsigned short Ah[2][2048], Al[2][2048];  // [64][32]
  __shared__ unsigned short Bh[2][4096], Bl[2][4096];  // [128][32]
  __shared__ float raw[64][97];                        // +1 pad: no stride-96 conflicts

  const int tid = threadIdx.x;
  const int m0 = blockIdx.x * 64;
  const int w = tid >> 6, lane = tid & 63;
  const int wr = w >> 1, wc = w & 1;
  const int l15 = lane & 15, lg = lane >> 4;
  const int arow = tid >> 2, ac8 = (tid & 3) << 3;

  const unsigned short* hhb = hh + (size_t)(m0 + arow) * HID + ac8;
  const unsigned short* hlb = hl + (size_t)(m0 + arow) * HID + ac8;
  const unsigned short* w2hb = w2h + (size_t)arow * HID + ac8;
  const unsigned short* w2lb = w2l + (size_t)arow * HID + ac8;

  f32x4 acc[2][3] = {};

#define G2_STAGE(kt, bf) { \
    gload16(hhb + (kt) * 32, &Ah[bf][(w << 9)]); \
    gload16(hlb + (kt) * 32, &Al[bf][(w << 9)]); \
    gload16(w2hb + (kt) * 32,            &Bh[bf][(w << 9)]); \
    gload16(w2hb + (kt) * 32 + 64 * HID, &Bh[bf][2048 + (w << 9)]); \
    gload16(w2lb + (kt) * 32,            &Bl[bf][(w << 9)]); \
    gload16(w2lb + (kt) * 32 + 64 * HID, &Bl[bf][2048 + (w << 9)]); }

#define G2_COMPUTE(bf) { \
    bf16x8 ah2[2], al2[2], bh2[3], bl2[3]; \
    _Pragma("unroll") \
    for (int mf = 0; mf < 2; mf++) { \
      const int o_ = ((wr * 32 + mf * 16 + l15) << 5) + (lg << 3); \
      ah2[mf] = ldfrag(&Ah[bf][o_]); \
      al2[mf] = ldfrag(&Al[bf][o_]); \
    } \
    _Pragma("unroll") \
    for (int nf = 0; nf < 3; nf++) { \
      const int o_ = ((wc * 48 + nf * 16 + l15) << 5) + (lg << 3); \
      bh2[nf] = ldfrag(&Bh[bf][o_]); \
      bl2[nf] = ldfrag(&Bl[bf][o_]); \
    } \
    _Pragma("unroll") \
    for (int mf = 0; mf < 2; mf++) { \
      _Pragma("unroll") \
      for (int nf = 0; nf < 3; nf++) { \
        acc[mf][nf] = mfma16(ah2[mf], bh2[nf], acc[mf][nf]); \
        acc[mf][nf] = mfma16(al2[mf], bh2[nf], acc[mf][nf]); \
        acc[mf][nf] = mfma16(ah2[mf], bl2[nf], acc[mf][nf]); \
      } } }

  G2_STAGE(0, 0);
  __syncthreads();
#pragma unroll 2
  for (int kt = 0; kt < 16; kt++) {
    const int cur = kt & 1, nx = cur ^ 1;
    if (kt < 15) G2_STAGE(kt + 1, nx);
    G2_COMPUTE(cur);
    __syncthreads();
  }

  // acc -> raw LDS (raw = h @ W2, no bias yet; cols 92..95 are zero via W2T pad)
#pragma unroll
  for (int mf = 0; mf < 2; mf++) {
#pragma unroll
    for (int nf = 0; nf < 3; nf++) {
#pragma unroll
      for (int r = 0; r < 4; r++) {
        const int ml = wr * 32 + mf * 16 + (lg << 2) + r;
        const int nl = wc * 48 + nf * 16 + l15;
        raw[ml][nl] = acc[mf][nf][r];
      }
    }
  }
  __syncthreads();

  const size_t OFFB = (size_t)BROWS * 72;   // offsets section
  const size_t LENB = (size_t)BROWS * 144;  // length section

  // phase 1: per (row, joint) -> direction*length, write offsets+length, off in-place
  for (int task = tid; task < 64 * 24; task += 256) {
    const int row = task / 24;
    const int j = task - row * 24;
    const int gm = m0 + row;
    float* orow = out + OFFB + (size_t)gm * 72;
    if (j == 0) {
      orow[0] = 0.0f; orow[1] = 0.0f; orow[2] = 0.0f;
    } else {
      const int c0 = (j - 1) * 4;
      const float vx = raw[row][c0 + 0] + b2[c0 + 0];
      const float vy = raw[row][c0 + 1] + b2[c0 + 1];
      const float vz = raw[row][c0 + 2] + b2[c0 + 2];
      const float wvv = raw[row][c0 + 3] + b2[c0 + 3];
      const float nrm = sqrtf(vx * vx + vy * vy + vz * vz);
      const float inv = 1.0f / fmaxf(nrm, 1e-12f);
      const float len = fmaxf(wvv, 0.0f) + log1pf(expf(-fabsf(wvv)));  // softplus
      const float sc = inv * len;
      const float ox = vx * sc, oy = vy * sc, oz = vz * sc;
      orow[j * 3 + 0] = ox; orow[j * 3 + 1] = oy; orow[j * 3 + 2] = oz;
      out[LENB + (size_t)gm * 23 + (j - 1)] = len;
      raw[row][c0 + 0] = ox; raw[row][c0 + 1] = oy; raw[row][c0 + 2] = oz;
    }
  }
  __syncthreads();

  // phase 2: forward kinematics, one thread per row, fully static unroll
  if (tid < 64) {
    constexpr int PAR[24] = {-1, 0, 0, 0, 1, 2, 3, 4, 5, 6, 7, 8,
                             9, 9, 9, 12, 13, 14, 16, 17, 18, 19, 20, 21};
    const int gm = m0 + tid;
    float e[72];
    e[0] = 0.0f; e[1] = 0.0f; e[2] = 0.0f;
#pragma unroll
    for (int j = 1; j < 24; j++) {
      const int p = PAR[j];
      const int c0 = (j - 1) * 4;
      e[3 * j + 0] = e[3 * p + 0] + raw[tid][c0 + 0];
      e[3 * j + 1] = e[3 * p + 1] + raw[tid][c0 + 1];
      e[3 * j + 2] = e[3 * p + 2] + raw[tid][c0 + 2];
    }
    float4* jo = (float4*)(out + (size_t)gm * 72);
#pragma unroll
    for (int q = 0; q < 18; q++)
      jo[q] = make_float4(e[4 * q + 0], e[4 * q + 1], e[4 * q + 2], e[4 * q + 3]);
  }
}

extern "C" void kernel_launch(void* const* d_in, const int* in_sizes, int n_in,
                              void* d_out, int out_size, void* d_ws, size_t ws_size,
                              hipStream_t stream) {
  const float* z = (const float*)d_in[0];
  const float* W1 = (const float*)d_in[1];
  const float* b1 = (const float*)d_in[2];
  const float* W2 = (const float*)d_in[3];
  const float* b2 = (const float*)d_in[4];
  float* out = (float*)d_out;

  char* ws = (char*)d_ws;
  unsigned short* w1f = (unsigned short*)(ws);                                  // 2 MB
  unsigned short* w2h = (unsigned short*)(ws + (2 << 20));                      // 128 KB
  unsigned short* w2l = (unsigned short*)(ws + (2 << 20) + 131072);             // 128 KB
  unsigned short* hh = (unsigned short*)(ws + ((size_t)4 << 20));               // 32 MB
  unsigned short* hl = (unsigned short*)(ws + ((size_t)4 << 20) + ((size_t)32 << 20));  // 32 MB

  hipFuncSetAttribute((const void*)k_gemm1,
                      hipFuncAttributeMaxDynamicSharedMemorySize, 65536);

  hipLaunchKernelGGL(k_prep_w1f, dim3(512), dim3(256), 0, stream, W1, w1f);
  hipLaunchKernelGGL(k_prep_w2t, dim3(256), dim3(256), 0, stream, W2, w2h, w2l);
  hipLaunchKernelGGL(k_gemm1, dim3(512), dim3(256), 65536, stream, z, w1f, b1, hh, hl);
  hipLaunchKernelGGL(k_gemm2, dim3(512), dim3(256), 0, stream, hh, hl, w2h, w2l, b2, out);
}